// Round 1
// baseline (237.810 us; speedup 1.0000x reference)
//
#include <hip/hip_runtime.h>
#include <hip/hip_bf16.h>

#define C_LEN 8192
#define Q_LEN 1024
#define DDIM  1024

typedef __attribute__((ext_vector_type(8))) short short8;
typedef __attribute__((ext_vector_type(4))) float f32x4;

// bf16 helpers (RNE), independent of __hip_bfloat16 internals
static __device__ __forceinline__ unsigned short f2bf(float f){
  unsigned u = __float_as_uint(f);
  unsigned rounding = 0x7fffu + ((u >> 16) & 1u);
  return (unsigned short)((u + rounding) >> 16);
}
static __device__ __forceinline__ float bf2f(unsigned short b){
  return __uint_as_float(((unsigned)b) << 16);
}

static __device__ __forceinline__ float waveRedSum(float v){
  #pragma unroll
  for(int o=32;o;o>>=1) v += __shfl_down(v,o);
  return v;
}
static __device__ __forceinline__ float waveRedMax(float v){
  #pragma unroll
  for(int o=32;o;o>>=1) v = fmaxf(v,__shfl_down(v,o));
  return v;
}

// One pass over H: Abf = bf16(H * w_qc), c_term = H@w_c + b_c, rowb = rowmax(H)
__global__ void prep_H(const float* __restrict__ H, const float* __restrict__ w_qc,
                       const float* __restrict__ w_c, const float* __restrict__ b_c,
                       unsigned short* __restrict__ Abf, float* __restrict__ c_term,
                       float* __restrict__ rowb){
  const int c = blockIdx.x, t = threadIdx.x;
  float4 h   = reinterpret_cast<const float4*>(H + (size_t)c*DDIM)[t];
  float4 wqc = reinterpret_cast<const float4*>(w_qc)[t];
  float4 wc  = reinterpret_cast<const float4*>(w_c)[t];
  float dot = h.x*wc.x + h.y*wc.y + h.z*wc.z + h.w*wc.w;
  float mx  = fmaxf(fmaxf(h.x,h.y), fmaxf(h.z,h.w));
  ushort4 o;
  o.x=f2bf(h.x*wqc.x); o.y=f2bf(h.y*wqc.y); o.z=f2bf(h.z*wqc.z); o.w=f2bf(h.w*wqc.w);
  reinterpret_cast<ushort4*>(Abf)[(size_t)c*256 + t] = o;
  __shared__ float sd[4], sm[4];
  int w=t>>6, l=t&63;
  dot = waveRedSum(dot); mx = waveRedMax(mx);
  if(l==0){ sd[w]=dot; sm[w]=mx; }
  __syncthreads();
  if(t==0){
    c_term[c] = sd[0]+sd[1]+sd[2]+sd[3] + b_c[0];
    rowb[c]   = fmaxf(fmaxf(sm[0],sm[1]), fmaxf(sm[2],sm[3]));
  }
}

// One pass over U: Ubf = bf16(U), q_term = U@w_q + b_q
__global__ void prep_U(const float* __restrict__ U, const float* __restrict__ w_q,
                       const float* __restrict__ b_q, unsigned short* __restrict__ Ubf,
                       float* __restrict__ q_term){
  const int qr = blockIdx.x, t = threadIdx.x;
  float4 u  = reinterpret_cast<const float4*>(U + (size_t)qr*DDIM)[t];
  float4 wq = reinterpret_cast<const float4*>(w_q)[t];
  float dot = u.x*wq.x + u.y*wq.y + u.z*wq.z + u.w*wq.w;
  ushort4 o; o.x=f2bf(u.x); o.y=f2bf(u.y); o.z=f2bf(u.z); o.w=f2bf(u.w);
  reinterpret_cast<ushort4*>(Ubf)[(size_t)qr*256 + t] = o;
  __shared__ float sd[4];
  int w=t>>6, l=t&63;
  dot = waveRedSum(dot);
  if(l==0) sd[w]=dot;
  __syncthreads();
  if(t==0) q_term[qr] = sd[0]+sd[1]+sd[2]+sd[3] + b_q[0];
}

// Ut[d][q] = bf16(U[q][d]) via LDS 64x64 tiles
__global__ void transpose_U(const float* __restrict__ U, unsigned short* __restrict__ Ut){
  __shared__ float tile[64][65];
  const int t = threadIdx.x;
  const int q0 = blockIdx.y*64, d0 = blockIdx.x*64;
  #pragma unroll
  for(int i=0;i<16;i++){
    int idx = i*256 + t, r = idx>>6, col = idx&63;
    tile[r][col] = U[(size_t)(q0+r)*DDIM + d0 + col];
  }
  __syncthreads();
  #pragma unroll
  for(int i=0;i<16;i++){
    int idx = i*256 + t, r = idx>>6, col = idx&63;
    Ut[(size_t)(d0+r)*Q_LEN + q0 + col] = f2bf(tile[col][r]);
  }
}

// C[m][n] = sum_k A[m][k]*B[n][k]  (+ rowAdd[m] + colAdd[n] + addC) ; bf16 in, f32 out
// 128x128 block tile, BK=32, 256 threads = 4 waves (2x2 of 64x64), 4x4 MFMA tiles/wave
template<int ADD>
__global__ __launch_bounds__(256)
void gemm_bt(const unsigned short* __restrict__ A, const unsigned short* __restrict__ B,
             float* __restrict__ C, int M, int N, int K,
             const float* __restrict__ rowAdd, const float* __restrict__ colAdd,
             const float* __restrict__ addC){
  __shared__ unsigned short As[128][40]; // +8 pad: stride 80B kills 8-way bank conflict
  __shared__ unsigned short Bs[128][40];
  const int t = threadIdx.x;
  const int lane = t & 63, wave = t >> 6;
  const int wm = wave & 1, wn = wave >> 1;
  const int lr = lane & 15, quad = lane >> 4;
  const int bm = blockIdx.x * 128, bn = blockIdx.y * 128;
  const int sr = t >> 2;        // staging row within 64-row half
  const int sc = (t & 3) * 8;   // staging k-col (8 bf16 = 16B)

  f32x4 acc[4][4];
  #pragma unroll
  for(int i=0;i<4;i++)
    #pragma unroll
    for(int j=0;j<4;j++) acc[i][j] = (f32x4){0.f,0.f,0.f,0.f};

  for(int k0=0;k0<K;k0+=32){
    #pragma unroll
    for(int h=0; h<2; h++){
      int row = h*64 + sr;
      uint4 va = *reinterpret_cast<const uint4*>(A + (size_t)(bm+row)*K + k0 + sc);
      *reinterpret_cast<uint4*>(&As[row][sc]) = va;
      uint4 vb = *reinterpret_cast<const uint4*>(B + (size_t)(bn+row)*K + k0 + sc);
      *reinterpret_cast<uint4*>(&Bs[row][sc]) = vb;
    }
    __syncthreads();
    short8 af[4], bfr[4];
    #pragma unroll
    for(int i=0;i<4;i++){
      af[i]  = *reinterpret_cast<const short8*>(&As[wm*64 + i*16 + lr][quad*8]);
      bfr[i] = *reinterpret_cast<const short8*>(&Bs[wn*64 + i*16 + lr][quad*8]);
    }
    #pragma unroll
    for(int i=0;i<4;i++)
      #pragma unroll
      for(int j=0;j<4;j++)
        acc[i][j] = __builtin_amdgcn_mfma_f32_16x16x32_bf16(af[i], bfr[j], acc[i][j], 0,0,0);
    __syncthreads();
  }

  const float ac = ADD ? addC[0] : 0.f;
  #pragma unroll
  for(int i=0;i<4;i++){
    int row0 = bm + wm*64 + i*16 + quad*4;
    #pragma unroll
    for(int j=0;j<4;j++){
      int col = bn + wn*64 + j*16 + lr;
      float cadd = ADD ? (colAdd[col] + ac) : 0.f;
      #pragma unroll
      for(int r=0;r<4;r++){
        float v = acc[i][j][r];
        if(ADD) v += rowAdd[row0+r] + cadd;
        C[(size_t)(row0+r)*N + col] = v;
      }
    }
  }
}

// monotonic float<->uint encode for atomicMax
__global__ void col_max(const float* __restrict__ S, unsigned* __restrict__ cmax){
  int q  = blockIdx.x*256 + threadIdx.x;
  int c0 = blockIdx.y*128;
  float mx = -3.4e38f;
  for(int c=c0;c<c0+128;c++) mx = fmaxf(mx, S[(size_t)c*Q_LEN + q]);
  unsigned u = __float_as_uint(mx);
  unsigned enc = (u & 0x80000000u) ? ~u : (u | 0x80000000u);
  atomicMax(&cmax[q], enc);
}

__global__ void col_expsum(const float* __restrict__ S, const unsigned* __restrict__ cmax,
                           float* __restrict__ csum, unsigned short* __restrict__ P){
  int q  = blockIdx.x*256 + threadIdx.x;
  int c0 = blockIdx.y*128;
  unsigned enc = cmax[q];
  unsigned u = (enc & 0x80000000u) ? (enc & 0x7fffffffu) : ~enc;
  float m = __uint_as_float(u);
  float s = 0.f;
  for(int c=c0;c<c0+128;c++){
    size_t idx = (size_t)c*Q_LEN + q;
    float e = __expf(S[idx] - m);
    P[idx] = f2bf(e);
    s += e;
  }
  atomicAdd(&csum[q], s);
}

// fold 1/colsum into Ut (2MB instead of rescaling 16MB of P)
__global__ void scale_Ut(unsigned short* __restrict__ Ut, const float* __restrict__ csum){
  int idx = blockIdx.x*256 + threadIdx.x;  // 1M elements
  int q = idx & (Q_LEN-1);
  Ut[idx] = f2bf(bf2f(Ut[idx]) / csum[q]);
}

__global__ void c2q_stats(const float* __restrict__ rowb, float* __restrict__ bstats){
  __shared__ float red[16];
  __shared__ float sbmax;
  int t = threadIdx.x; int w=t>>6, l=t&63;
  float mx=-3.4e38f;
  for(int c=t;c<C_LEN;c+=1024) mx=fmaxf(mx,rowb[c]);
  mx = waveRedMax(mx);
  if(!l) red[w]=mx;
  __syncthreads();
  if(t==0){ float m=red[0]; for(int i=1;i<16;i++) m=fmaxf(m,red[i]); sbmax=m; }
  __syncthreads();
  float bmax = sbmax;
  float s=0.f;
  for(int c=t;c<C_LEN;c+=1024) s += __expf(rowb[c]-bmax);
  s = waveRedSum(s);
  __syncthreads();
  if(!l) red[w]=s;
  __syncthreads();
  if(t==0){ float tot=0.f; for(int i=0;i<16;i++) tot+=red[i]; bstats[0]=bmax; bstats[1]=tot; }
}

__global__ void h_weighted(const float* __restrict__ H, const float* __restrict__ rowb,
                           const float* __restrict__ bstats, float* __restrict__ Hrow){
  int d  = blockIdx.x*256 + threadIdx.x;
  int c0 = blockIdx.y*256;
  float bmax = bstats[0], inv = 1.f/bstats[1];
  float acc = 0.f;
  for(int c=c0;c<c0+256;c++)
    acc += __expf(rowb[c]-bmax) * H[(size_t)c*DDIM + d];
  atomicAdd(&Hrow[d], acc*inv);
}

__global__ void bcast_H(const float* __restrict__ Hrow, float4* __restrict__ out4){
  int gid = blockIdx.x*256 + threadIdx.x;   // 2M float4s = 8M floats
  int d4 = gid & 255;
  out4[gid] = reinterpret_cast<const float4*>(Hrow)[d4];
}

extern "C" void kernel_launch(void* const* d_in, const int* in_sizes, int n_in,
                              void* d_out, int out_size, void* d_ws, size_t ws_size,
                              hipStream_t stream){
  const float* H    = (const float*)d_in[0];
  const float* U    = (const float*)d_in[1];
  const float* w_q  = (const float*)d_in[2];
  const float* b_q  = (const float*)d_in[3];
  const float* w_c  = (const float*)d_in[4];
  const float* b_c  = (const float*)d_in[5];
  const float* w_qc = (const float*)d_in[6];
  const float* b_qc = (const float*)d_in[7];
  float* out = (float*)d_out;
  char*  ws  = (char*)d_ws;

  float*          S    = (float*)(ws);                         // 32 MB
  unsigned short* P    = (unsigned short*)(ws + 33554432);     // 16 MB
  unsigned short* Abf  = (unsigned short*)(ws + 50331648);     // 16 MB
  unsigned short* Ubf  = (unsigned short*)(ws + 67108864);     //  2 MB
  unsigned short* Utb  = (unsigned short*)(ws + 69206016);     //  2 MB
  char* stats = ws + 71303168;
  unsigned* cmax  = (unsigned*)(stats);                        // 4 KB
  float*    csum  = (float*)(stats + 4096);                    // 4 KB
  float*    Hrow  = (float*)(stats + 8192);                    // 4 KB
  float*    cterm = (float*)(stats + 12288);                   // 32 KB
  float*    rowb  = (float*)(stats + 45056);                   // 32 KB
  float*    qterm = (float*)(stats + 77824);                   // 4 KB
  float*    bstat = (float*)(stats + 81920);

  hipMemsetAsync(stats, 0, 12288, stream);  // cmax=0 (=-inf encoded), csum=0, Hrow=0

  prep_H<<<C_LEN, 256, 0, stream>>>(H, w_qc, w_c, b_c, Abf, cterm, rowb);
  prep_U<<<Q_LEN, 256, 0, stream>>>(U, w_q, b_q, Ubf, qterm);
  transpose_U<<<dim3(16,16), 256, 0, stream>>>(U, Utb);

  gemm_bt<1><<<dim3(64,8), 256, 0, stream>>>(Abf, Ubf, S, C_LEN, Q_LEN, DDIM,
                                             cterm, qterm, b_qc);

  col_max   <<<dim3(4,64), 256, 0, stream>>>(S, cmax);
  col_expsum<<<dim3(4,64), 256, 0, stream>>>(S, cmax, csum, P);
  scale_Ut  <<<4096, 256, 0, stream>>>(Utb, csum);

  gemm_bt<0><<<dim3(64,8), 256, 0, stream>>>(P, Utb, out, C_LEN, DDIM, Q_LEN,
                                             nullptr, nullptr, nullptr);

  c2q_stats <<<1, 1024, 0, stream>>>(rowb, bstat);
  h_weighted<<<dim3(4,32), 256, 0, stream>>>(H, rowb, bstat, Hrow);
  bcast_H   <<<8192, 256, 0, stream>>>(Hrow, (float4*)(out + (size_t)C_LEN*DDIM));
}